// Round 16
// baseline (234.159 us; speedup 1.0000x reference)
//
#include <hip/hip_runtime.h>
#include <hip/hip_cooperative_groups.h>
#include <math.h>

namespace cg = cooperative_groups;

// Problem constants
// B=1, N=256, H=32, W=32, M=1024, C_LIDAR=C_RGB=64, K=16, S=3, MLP3=[128,64,64]

typedef _Float16 f16;
typedef __attribute__((ext_vector_type(4))) _Float16 f16x4;
typedef __attribute__((ext_vector_type(8))) _Float16 f16x8;
typedef __attribute__((ext_vector_type(4))) float f32x4;

// ---------------- workspace layout (float offsets) ----------------
constexpr int WS_XYZ  = 0;                  // 256*3
constexpr int WS_RF   = 768;                // 1024*64
constexpr int WS_RFI  = WS_RF   + 65536;    // 1024*3
constexpr int WS_SN   = WS_RFI  + 3072;     // (reused: RS/RD below)
constexpr int WS_RS   = WS_SN;              // 256 recip norms of wpts rows
constexpr int WS_RD   = WS_SN   + 256;      // 1024 recip norms of RF3 cols
constexpr int WS_WPT  = WS_SN   + 16384;    // 64*256 wpts^T (c-major)
constexpr int WS_SIM1 = WS_WPT  + 65536;    // 1024*256 sim1 TRANSPOSED [n][m]
constexpr int WS_RM1  = WS_SIM1 + 262144;   // 1024 max over n
constexpr int WS_CM1  = WS_RM1  + 1024;     // (unused)
constexpr int WS_PCT  = WS_CM1  + 256;      // 64*256 pcn^T (c-major)
constexpr int WS_IMGF = WS_PCT  + 16384;    // (unused)
constexpr int WS_PCN  = WS_IMGF + 65536;    // (unused, layout keep)
constexpr int WS_IMGN = WS_PCN  + 16384;    // 1024*64 normalized img_feats
constexpr int WS_SIM2 = WS_IMGN + 65536;    // 1024*256 sim2 TRANSPOSED [n][m]
constexpr int WS_RM2  = WS_SIM2 + 262144;   // 1024
constexpr int WS_CM2  = WS_RM2  + 1024;     // (unused)
constexpr int WS_B1   = WS_CM2  + 256;      // 256*128
constexpr int WS_B2   = WS_B1   + 32768;    // 1024*128
constexpr int WS_ATT  = WS_B2   + 131072;   // (unused)
constexpr int WS_UV   = WS_ATT  + 16384;    // 256*3
constexpr int WS_WIN  = WS_UV   + 768;      // 256
constexpr int WS_KNN  = WS_WIN  + 256;      // 256*16 ints
constexpr int WS_PM   = WS_KNN  + 4096;     // 256*8 partial max
constexpr int WS_PS   = WS_PM   + 2048;     // 256*8 partial sum
constexpr int WS_PATT = WS_PS   + 2048;     // 256*8*64 partial att
constexpr int WS_PUV  = WS_PATT + 131072;   // 256*8*3 partial uv
constexpr int WS_W11T = WS_PUV  + 6144;     // 8192 f16 (w1_1^T [col][k])
constexpr int WS_W12T = WS_W11T + 4096;     // 4096 f16 (w1_2^T [col][k])
constexpr int WS_G3   = WS_W12T + 2048;     // 1025*64 (MLP3 layer-1 per-pixel)
constexpr int WS_SIMF = WS_G3   + 65600;    // 256*1024*4 f16 (sim features)
// total ~= 7.06 MB

// ======================= device stage bodies (shared by both paths) ============

__device__ __forceinline__ void prep_body(int b, int t, float* ws, const float* wxyz,
        const float* lz, const float* RF3, const float* RFI, const float* w11,
        const float* w12, const float* wpts) {
    if (b < 319) {
        int i = b * 256 + t;
        if (i < 768) {
            int n = i / 3;
            ws[WS_XYZ + i] = wxyz[i] * lz[n];
        } else if (i < 768 + 65536) {
            int j = i - 768; int mm = j >> 6, c = j & 63;
            ws[WS_RF + j] = RF3[c * 1024 + mm];
        } else if (i < 768 + 65536 + 3072) {
            int j = i - (768 + 65536); int mm = j / 3, c = j - mm * 3;
            ws[WS_RFI + j] = RFI[c * 1024 + mm];
        } else if (i < 69376 + 8192) {
            int j = i - 69376; int col = j >> 7, k = j & 127;
            ((f16*)(ws + WS_W11T))[col * 128 + k] = (f16)w11[k * 64 + col];
        } else if (i < 69376 + 12288) {
            int j = i - (69376 + 8192); int col = j >> 6, k = j & 63;
            ((f16*)(ws + WS_W12T))[col * 64 + k] = (f16)w12[k * 64 + col];
        }
    } else if (b == 319) {
        int n = t;
        float s = 0.f;
        for (int c = 0; c < 64; c++) { float v = wpts[n * 64 + c]; s += v * v; }
        ws[WS_RS + n] = 1.f / fmaxf(sqrtf(s), 1e-12f);
    } else if (b < 324) {
        int m = (b - 320) * 256 + t;
        float s = 0.f;
        for (int c = 0; c < 64; c++) { float v = RF3[c * 1024 + m]; s += v * v; }
        ws[WS_RD + m] = 1.f / fmaxf(sqrtf(s), 1e-12f);
    } else {
        int i = (b - 324) * 256 + t;
        int c = i >> 8, n = i & 255;
        ws[WS_WPT + c * 256 + n] = wpts[n * 64 + c];
    }
}

// smem: px/py/pz/d2/rv (float[256] each), ri (int[256]), wred (float[4])
__device__ __forceinline__ void mid_body(int b, int t, float* ws, const float* wpts,
        const float* w30, const float* b30, const float* w10, const float* b10,
        float* px, float* py, float* pz, float* d2, float* rv, int* ri, float* wred) {
    if (b < 1024) {
        int m = b;
        int wave = t >> 6, lane = t & 63;
        const float* rf = ws + WS_RF;
        const float* wptsT = ws + WS_WPT;
        if (t < 64) px[t] = rf[m * 64 + t];   // dv[64]
        __syncthreads();
        float acc = 0.f;
        for (int c = 0; c < 64; c += 4) {
            acc += px[c]     * wptsT[c * 256 + t]
                 + px[c + 1] * wptsT[(c + 1) * 256 + t]
                 + px[c + 2] * wptsT[(c + 2) * 256 + t]
                 + px[c + 3] * wptsT[(c + 3) * 256 + t];
        }
        acc = acc * ws[WS_RD + m] * ws[WS_RS + t];
        ws[WS_SIM1 + t * 1024 + m] = acc;
        float mx = acc;
        for (int o = 32; o > 0; o >>= 1) mx = fmaxf(mx, __shfl_down(mx, o));
        if (lane == 0) wred[wave] = mx;
        __syncthreads();
        if (t == 0)
            ws[WS_RM1 + m] = fmaxf(fmaxf(wred[0], wred[1]), fmaxf(wred[2], wred[3]));
    } else if (b < 1281) {
        int m = (b - 1024) * 4 + (t >> 6), j = t & 63;
        if (m < 1025) {
            float acc;
            if (m < 1024) {
                float a0 = b30[j], a1 = 0.f, a2 = 0.f, a3 = 0.f;
                for (int i = 0; i < 3; i++) a0 += ws[WS_RFI + m * 3 + i] * w30[i * 64 + j];
                const float* rfm = ws + WS_RF + m * 64;
                const float* wp = w30 + 3 * 64 + j;
                for (int c = 0; c < 64; c += 4) {
                    a0 += rfm[c]     * wp[c * 64];
                    a1 += rfm[c + 1] * wp[(c + 1) * 64];
                    a2 += rfm[c + 2] * wp[(c + 2) * 64];
                    a3 += rfm[c + 3] * wp[(c + 3) * 64];
                }
                acc = (a0 + a1) + (a2 + a3);
            } else {
                acc = b30[j];
            }
            ws[WS_G3 + m * 64 + j] = fmaxf(acc, 0.f);
        }
    } else if (b < 1921) {
        int bb = (b - 1281) * 2 + (t >> 7);
        int j = t & 127;
        if (bb < 256) {
            int n = bb;
            float a0 = b10[j], a1 = 0.f, a2 = 0.f, a3 = 0.f;
            for (int i = 0; i < 3; i++) a0 += ws[WS_XYZ + n * 3 + i] * w10[i * 128 + j];
            const float* xp = wpts + n * 64;
            const float* wp = w10 + 6 * 128 + j;
            for (int c = 0; c < 64; c += 4) {
                a0 += xp[c]     * wp[c * 128];
                a1 += xp[c + 1] * wp[(c + 1) * 128];
                a2 += xp[c + 2] * wp[(c + 2) * 128];
                a3 += xp[c + 3] * wp[(c + 3) * 128];
            }
            ws[WS_B1 + n * 128 + j] = (a0 + a1) + (a2 + a3);
        } else {
            int m = bb - 256;
            float a0 = 0.f, a1 = 0.f, a2 = 0.f, a3 = 0.f;
            for (int i = 0; i < 3; i++) a0 += ws[WS_RFI + m * 3 + i] * w10[(3 + i) * 128 + j];
            const float* rfm = ws + WS_RF + m * 64;
            const float* wp = w10 + 70 * 128 + j;
            for (int c = 0; c < 64; c += 4) {
                a0 += rfm[c]     * wp[c * 128];
                a1 += rfm[c + 1] * wp[(c + 1) * 128];
                a2 += rfm[c + 2] * wp[(c + 2) * 128];
                a3 += rfm[c + 3] * wp[(c + 3) * 128];
            }
            ws[WS_B2 + m * 128 + j] = (a0 + a1) + (a2 + a3);
        }
    } else {
        // knn (LDS tree; do NOT replace with __shfl_down argmin — bad on gfx950, R3-R5)
        const float* xyz = ws + WS_XYZ;
        int* knn = (int*)(ws + WS_KNN);
        int n = b - 1921;
        px[t] = xyz[t * 3 + 0]; py[t] = xyz[t * 3 + 1]; pz[t] = xyz[t * 3 + 2];
        __syncthreads();
        float dx = px[t] - px[n], dy = py[t] - py[n], dz = pz[t] - pz[n];
        d2[t] = dx * dx + dy * dy + dz * dz;
        __syncthreads();
        for (int k = 0; k < 16; k++) {
            rv[t] = d2[t]; ri[t] = t;
            __syncthreads();
            for (int s = 128; s > 0; s >>= 1) {
                if (t < s) {
                    float v2 = rv[t + s]; int i2 = ri[t + s];
                    if (v2 < rv[t] || (v2 == rv[t] && i2 < ri[t])) { rv[t] = v2; ri[t] = i2; }
                }
                __syncthreads();
            }
            if (t == 0) { knn[n * 16 + k] = ri[0]; d2[ri[0]] = INFINITY; }
            __syncthreads();
        }
    }
}

// smem: sbuf float[4896], small1 float[36], small2 float[36], kn int[16]
__device__ __forceinline__ void mlp23_body(int b, int t, float* ws, const float* wpts,
        const float* w20, const float* b20, const float* w21, const float* b21,
        const float* w22, const float* b22,
        const float* w31, const float* b31, const float* w32, const float* b32,
        float* sbuf, float* small1, float* small2, int* kn) {
    if (b < 256) {
        int n = b;
        float* x  = sbuf;
        float* hA = sbuf + 1088;
        float* hB = sbuf + 2176;
        const float* xyz = ws + WS_XYZ;
        const int* knn = (const int*)(ws + WS_KNN);
        if (t < 16) kn[t] = knn[n * 16 + t];
        __syncthreads();
        for (int i = t; i < 1024; i += 256) {
            int k = i >> 6, c = i & 63;
            x[k * 68 + c] = wpts[kn[k] * 64 + c];
        }
        if (t < 16) {
            int i = kn[t];
            float dx = xyz[i * 3 + 0] - xyz[n * 3 + 0];
            float dy = xyz[i * 3 + 1] - xyz[n * 3 + 1];
            float dz = xyz[i * 3 + 2] - xyz[n * 3 + 2];
            x[t * 68 + 64] = dx; x[t * 68 + 65] = dy; x[t * 68 + 66] = dz;
            x[t * 68 + 67] = sqrtf(dx * dx + dy * dy + dz * dz);
        }
        __syncthreads();
        for (int o = t; o < 1024; o += 256) {
            int k = o >> 6, j = o & 63;
            float a0 = b20[j], a1 = 0.f, a2 = 0.f, a3 = 0.f;
            const float* xr = &x[k * 68];
            const float* wp = w20 + j;
            for (int i = 0; i < 68; i += 4) {
                a0 += xr[i]     * wp[i * 64];
                a1 += xr[i + 1] * wp[(i + 1) * 64];
                a2 += xr[i + 2] * wp[(i + 2) * 64];
                a3 += xr[i + 3] * wp[(i + 3) * 64];
            }
            hA[k * 68 + j] = fmaxf((a0 + a1) + (a2 + a3), 0.f);
        }
        __syncthreads();
        for (int o = t; o < 1024; o += 256) {
            int k = o >> 6, j = o & 63;
            float a0 = b21[j], a1 = 0.f, a2 = 0.f, a3 = 0.f;
            const float* xr = &hA[k * 68];
            const float* wp = w21 + j;
            for (int i = 0; i < 64; i += 4) {
                a0 += xr[i]     * wp[i * 64];
                a1 += xr[i + 1] * wp[(i + 1) * 64];
                a2 += xr[i + 2] * wp[(i + 2) * 64];
                a3 += xr[i + 3] * wp[(i + 3) * 64];
            }
            hB[k * 68 + j] = fmaxf((a0 + a1) + (a2 + a3), 0.f);
        }
        __syncthreads();
        for (int o = t; o < 1024; o += 256) {
            int k = o >> 6, j = o & 63;
            float a0 = b22[j], a1 = 0.f, a2 = 0.f, a3 = 0.f;
            const float* xr = &hB[k * 68];
            const float* wp = w22 + j;
            for (int i = 0; i < 64; i += 4) {
                a0 += xr[i]     * wp[i * 64];
                a1 += xr[i + 1] * wp[(i + 1) * 64];
                a2 += xr[i + 2] * wp[(i + 2) * 64];
                a3 += xr[i + 3] * wp[(i + 3) * 64];
            }
            hA[k * 68 + j] = fmaxf((a0 + a1) + (a2 + a3), 0.f);
        }
        __syncthreads();
        if (t < 16) {
            float mx = -INFINITY;
            for (int j = 0; j < 64; j++) mx = fmaxf(mx, hA[t * 68 + j]);
            small1[t] = mx;
        }
        __syncthreads();
        if (t < 16) {
            float mx = -INFINITY;
            for (int k = 0; k < 16; k++) mx = fmaxf(mx, small1[k]);
            float sum = 0.f;
            for (int k = 0; k < 16; k++) sum += expf(small1[k] - mx);
            small2[t] = expf(small1[t] - mx) / sum;
        }
        __syncthreads();
        if (t < 64) {
            float acc = 0.f;
            for (int k = 0; k < 16; k++) acc += small2[k] * x[k * 68 + t];
            float s = acc * acc;
            for (int o = 32; o > 0; o >>= 1) s += __shfl_down(s, o);
            s = __shfl(s, 0);
            ws[WS_PCT + t * 256 + n] = acc / fmaxf(sqrtf(s), 1e-12f);  // pcn^T
        }
    } else {
        int m0 = (b - 256) * 4;
        float* x1 = sbuf;
        float* h2 = sbuf + 2448;
        const float* G = ws + WS_G3;
        const float* rf = ws + WS_RF;
        for (int i = t; i < 36 * 64; i += 256) {
            int row = i >> 6, c = i & 63;
            int mi = row / 9, kk = row - mi * 9;
            int m = m0 + mi; int y = m >> 5, x = m & 31;
            int dy = kk / 3 - 1, dx = kk % 3 - 1;
            int ny = y + dy, nx = x + dx;
            bool val = (ny >= 0 && ny < 32 && nx >= 0 && nx < 32);
            int idx = val ? (ny * 32 + nx) : 1024;
            x1[row * 68 + c] = G[idx * 64 + c];
        }
        __syncthreads();
        for (int o = t; o < 36 * 64; o += 256) {
            int row = o >> 6, c = o & 63;
            float a0 = b31[c], a1 = 0.f, a2 = 0.f, a3 = 0.f;
            const float* xr = &x1[row * 68];
            const float* wp = w31 + c;
            for (int i = 0; i < 64; i += 4) {
                a0 += xr[i]     * wp[i * 64];
                a1 += xr[i + 1] * wp[(i + 1) * 64];
                a2 += xr[i + 2] * wp[(i + 2) * 64];
                a3 += xr[i + 3] * wp[(i + 3) * 64];
            }
            h2[row * 68 + c] = fmaxf((a0 + a1) + (a2 + a3), 0.f);
        }
        __syncthreads();
        for (int o = t; o < 36 * 64; o += 256) {
            int row = o >> 6, c = o & 63;
            float a0 = b32[c], a1 = 0.f, a2 = 0.f, a3 = 0.f;
            const float* xr = &h2[row * 68];
            const float* wp = w32 + c;
            for (int i = 0; i < 64; i += 4) {
                a0 += xr[i]     * wp[i * 64];
                a1 += xr[i + 1] * wp[(i + 1) * 64];
                a2 += xr[i + 2] * wp[(i + 2) * 64];
                a3 += xr[i + 3] * wp[(i + 3) * 64];
            }
            x1[row * 68 + c] = fmaxf((a0 + a1) + (a2 + a3), 0.f);
        }
        __syncthreads();
        if (t < 36) {
            float mx = -INFINITY;
            for (int c = 0; c < 64; c++) mx = fmaxf(mx, x1[t * 68 + c]);
            small1[t] = mx;
        }
        __syncthreads();
        if (t < 36) {
            int mi = t / 9;
            float mx = -INFINITY;
            for (int k = 0; k < 9; k++) mx = fmaxf(mx, small1[mi * 9 + k]);
            float sum = 0.f;
            for (int k = 0; k < 9; k++) sum += expf(small1[mi * 9 + k] - mx);
            small2[t] = expf(small1[t] - mx) / sum;
        }
        __syncthreads();
        {
            int mi = t >> 6, c = t & 63;
            int m = m0 + mi; int y = m >> 5, x = m & 31;
            float acc = 0.f;
            for (int kk = 0; kk < 9; kk++) {
                int dy = kk / 3 - 1, dx = kk % 3 - 1;
                int ny = y + dy, nx = x + dx;
                bool val = (ny >= 0 && ny < 32 && nx >= 0 && nx < 32);
                if (val) acc += small2[mi * 9 + kk] * rf[(ny * 32 + nx) * 64 + c];
            }
            float s = acc * acc;
            for (int o = 32; o > 0; o >>= 1) s += __shfl_down(s, o);
            s = __shfl(s, 0);
            ws[WS_IMGN + m * 64 + c] = acc / fmaxf(sqrtf(s), 1e-12f);
        }
    }
}

// smem: dv float[64], wred float[4]
__device__ __forceinline__ void sim2_body(int m, int t, float* ws, float* dv, float* wred) {
    int wave = t >> 6, lane = t & 63;
    if (t < 64) dv[t] = ws[WS_IMGN + m * 64 + t];
    __syncthreads();
    const float* pcnT = ws + WS_PCT;
    float acc = 0.f;
    for (int c = 0; c < 64; c += 4) {
        acc += dv[c]     * pcnT[c * 256 + t]
             + dv[c + 1] * pcnT[(c + 1) * 256 + t]
             + dv[c + 2] * pcnT[(c + 2) * 256 + t]
             + dv[c + 3] * pcnT[(c + 3) * 256 + t];
    }
    ws[WS_SIM2 + t * 1024 + m] = acc;
    float mx = acc;
    for (int o = 32; o > 0; o >>= 1) mx = fmaxf(mx, __shfl_down(mx, o));
    if (lane == 0) wred[wave] = mx;
    __syncthreads();
    if (t == 0)
        ws[WS_RM2 + m] = fmaxf(fmaxf(wred[0], wred[1]), fmaxf(wred[2], wred[3]));
}

// smem: wred1 float[4], wred2 float[4]
__device__ __forceinline__ void simfeat_body(int n, int t, float* ws,
                                             float* wred1, float* wred2) {
    int wave = t >> 6, lane = t & 63;
    const float* sim1 = ws + WS_SIM1;  const float* rm1g = ws + WS_RM1;
    const float* sim2 = ws + WS_SIM2;  const float* rm2g = ws + WS_RM2;
    f16* simfg = (f16*)(ws + WS_SIMF);
    float s1v[4], s2v[4];
    float mx1 = -INFINITY, mx2 = -INFINITY;
    for (int j = 0; j < 4; j++) {
        int m = t + j * 256;
        s1v[j] = sim1[n * 1024 + m]; mx1 = fmaxf(mx1, s1v[j]);
        s2v[j] = sim2[n * 1024 + m]; mx2 = fmaxf(mx2, s2v[j]);
    }
    float m1 = mx1, m2 = mx2;
    for (int o = 32; o > 0; o >>= 1) {
        m1 = fmaxf(m1, __shfl_down(m1, o));
        m2 = fmaxf(m2, __shfl_down(m2, o));
    }
    if (lane == 0) { wred1[wave] = m1; wred2[wave] = m2; }
    __syncthreads();
    float cm1 = fmaxf(fmaxf(wred1[0], wred1[1]), fmaxf(wred1[2], wred1[3]));
    float cm2 = fmaxf(fmaxf(wred2[0], wred2[1]), fmaxf(wred2[2], wred2[3]));
    for (int j = 0; j < 4; j++) {
        int m = t + j * 256;
        float r1 = rm1g[m], r2 = rm2g[m];
        float f0 = s1v[j] / (cm1 + 1e-6f);
        float f1 = s1v[j] / (r1 + 1e-10f);
        float f2 = s2v[j] / (cm2 + 1e-6f);
        float f3 = s2v[j] / (r2 + 1e-10f);
        *(f16x4*)&simfg[(n * 1024 + m) * 4] =
            (f16x4){(f16)f0, (f16)f1, (f16)f2, (f16)f3};
    }
}

// smem: H1h f16[64*136], H2h f16[64*72], base1n float[128], simw float[512],
// rmPart float[4*64]. B2f/B3f/bias preloaded by caller (loop-invariant).
__device__ __forceinline__ void mlp1_body(int n, int seg, int t, float* ws,
        const f16x8* B2f, const f16x8* B3f, float bias2, float bias3,
        f16* H1h, f16* H2h, float* base1n, float* simw, float* rmPart) {
    int wave = t >> 6, lane = t & 63, q = lane >> 4, l16 = lane & 15;
    int col = wave * 16 + l16;
    const float* base2 = ws + WS_B2;
    const float* rfig = ws + WS_RFI;
    const f16* simfg = (const f16*)(ws + WS_SIMF);
    if (t < 128) base1n[t] = ws[WS_B1 + n * 128 + t];
    float attAcc = 0.f;
    float uv0 = 0.f, uv1 = 0.f, uv2 = 0.f;
    float Mv = -INFINITY, Sv = 0.f;
    int mBeg = seg * 128;
    __syncthreads();
    for (int c4 = 0; c4 < 2; c4++) {
        int m0 = mBeg + c4 * 64;
        for (int idx = t; idx < 2048; idx += 256) {
            int row = idx >> 5, k4 = (idx & 31) * 4;
            int m = m0 + row;
            f16x4 sf = *(const f16x4*)&simfg[(n * 1024 + m) * 4];
            float s0 = (float)sf[0], s1 = (float)sf[1], s2 = (float)sf[2], s3 = (float)sf[3];
            float4 bs = *(const float4*)&base2[m * 128 + k4];
            float4 b1v = *(const float4*)&base1n[k4];
            float4 w0v = *(const float4*)&simw[k4];
            float4 w1v = *(const float4*)&simw[128 + k4];
            float4 w2v = *(const float4*)&simw[256 + k4];
            float4 w3v = *(const float4*)&simw[384 + k4];
            float v0 = b1v.x + bs.x + s0 * w0v.x + s1 * w1v.x + s2 * w2v.x + s3 * w3v.x;
            float v1 = b1v.y + bs.y + s0 * w0v.y + s1 * w1v.y + s2 * w2v.y + s3 * w3v.y;
            float v2 = b1v.z + bs.z + s0 * w0v.z + s1 * w1v.z + s2 * w2v.z + s3 * w3v.z;
            float v3 = b1v.w + bs.w + s0 * w0v.w + s1 * w1v.w + s2 * w2v.w + s3 * w3v.w;
            *(f16x4*)&H1h[row * 136 + k4] = (f16x4){
                (f16)fmaxf(v0, 0.f), (f16)fmaxf(v1, 0.f),
                (f16)fmaxf(v2, 0.f), (f16)fmaxf(v3, 0.f)};
        }
        __syncthreads();
        f32x4 a[4];
        for (int tl = 0; tl < 4; tl++) a[tl] = (f32x4){bias2, bias2, bias2, bias2};
        for (int s = 0; s < 4; s++)
            for (int tl = 0; tl < 4; tl++) {
                f16x8 f = *(const f16x8*)&H1h[(tl * 16 + l16) * 136 + s * 32 + q * 8];
                a[tl] = __builtin_amdgcn_mfma_f32_16x16x32_f16(f, B2f[s], a[tl], 0, 0, 0);
            }
        for (int tl = 0; tl < 4; tl++)
            for (int r = 0; r < 4; r++)
                H2h[(tl * 16 + q * 4 + r) * 72 + col] = (f16)fmaxf(a[tl][r], 0.f);
        __syncthreads();
        f32x4 c3[4];
        for (int tl = 0; tl < 4; tl++) c3[tl] = (f32x4){bias3, bias3, bias3, bias3};
        for (int s = 0; s < 2; s++)
            for (int tl = 0; tl < 4; tl++) {
                f16x8 f = *(const f16x8*)&H2h[(tl * 16 + l16) * 72 + s * 32 + q * 8];
                c3[tl] = __builtin_amdgcn_mfma_f32_16x16x32_f16(f, B3f[s], c3[tl], 0, 0, 0);
            }
        for (int tl = 0; tl < 4; tl++)
            for (int r = 0; r < 4; r++)
                c3[tl][r] = fmaxf(c3[tl][r], 0.f);
        for (int tl = 0; tl < 4; tl++)
            for (int r = 0; r < 4; r++) {
                float v = c3[tl][r];
                v = fmaxf(v, __shfl_xor(v, 1));
                v = fmaxf(v, __shfl_xor(v, 2));
                v = fmaxf(v, __shfl_xor(v, 4));
                v = fmaxf(v, __shfl_xor(v, 8));
                if (l16 == 0) rmPart[wave * 64 + tl * 16 + q * 4 + r] = v;
            }
        __syncthreads();
        float rmv = fmaxf(fmaxf(rmPart[0 * 64 + lane], rmPart[1 * 64 + lane]),
                          fmaxf(rmPart[2 * 64 + lane], rmPart[3 * 64 + lane]));
        float tv = rmv;
        for (int off = 32; off > 0; off >>= 1) tv = fmaxf(tv, __shfl_xor(tv, off));
        float newM = fmaxf(Mv, tv);
        float rescale = __expf(Mv - newM);
        float ewv = __expf(rmv - newM);
        Mv = newM;
        float se = ewv;
        for (int off = 32; off > 0; off >>= 1) se += __shfl_xor(se, off);
        Sv = Sv * rescale + se;
        float ap = 0.f;
        for (int tl = 0; tl < 4; tl++)
            for (int r = 0; r < 4; r++)
                ap += __shfl(ewv, tl * 16 + q * 4 + r) * c3[tl][r];
        ap += __shfl_xor(ap, 16);
        ap += __shfl_xor(ap, 32);
        if (lane < 16) attAcc = attAcc * rescale + ap;
        if (wave == 0) {
            const float* rp = &rfig[(m0 + lane) * 3];
            float u0 = ewv * rp[0], u1 = ewv * rp[1], u2 = ewv * rp[2];
            for (int off = 32; off > 0; off >>= 1) {
                u0 += __shfl_xor(u0, off);
                u1 += __shfl_xor(u1, off);
                u2 += __shfl_xor(u2, off);
            }
            uv0 = uv0 * rescale + u0;
            uv1 = uv1 * rescale + u1;
            uv2 = uv2 * rescale + u2;
        }
    }
    int p = n * 8 + seg;
    if (t == 0) {
        ws[WS_PM + p] = Mv; ws[WS_PS + p] = Sv;
        ws[WS_PUV + p * 3 + 0] = uv0;
        ws[WS_PUV + p * 3 + 1] = uv1;
        ws[WS_PUV + p * 3 + 2] = uv2;
    }
    if (lane < 16) ws[WS_PATT + p * 64 + wave * 16 + lane] = attAcc;
}

// smem: av float[64], ha float[64], hb float[128], lg float[2]
__device__ __forceinline__ void combinehead_body(int n, int t, float* ws,
        const float* wm0, const float* bm0, const float* wm1, const float* bm1,
        const float* wm2, const float* bm2, float* out,
        float* av, float* ha, float* hb, float* lg) {
    float pm[8], e[8];
    float M = -INFINITY;
    for (int s = 0; s < 8; s++) { pm[s] = ws[WS_PM + n * 8 + s]; M = fmaxf(M, pm[s]); }
    float S = 0.f;
    for (int s = 0; s < 8; s++) { e[s] = expf(pm[s] - M); S += ws[WS_PS + n * 8 + s] * e[s]; }
    if (t < 64) {
        float acc = 0.f;
        for (int s = 0; s < 8; s++) acc += ws[WS_PATT + (n * 8 + s) * 64 + t] * e[s];
        av[t] = acc / S;
    } else if (t < 67) {
        int c = t - 64; float acc = 0.f;
        for (int s = 0; s < 8; s++) acc += ws[WS_PUV + (n * 8 + s) * 3 + c] * e[s];
        ws[WS_UV + n * 3 + c] = acc / S;
    }
    __syncthreads();
    if (t < 64) {
        float acc = bm0[t];
        for (int i = 0; i < 64; i++) acc += av[i] * wm0[i * 64 + t];
        ha[t] = fmaxf(acc, 0.f);
    }
    __syncthreads();
    if (t < 128) {
        float acc = bm1[t];
        for (int i = 0; i < 64; i++) acc += ha[i] * wm1[i * 128 + t];
        hb[t] = fmaxf(acc, 0.f);
    }
    __syncthreads();
    if (t < 2) {
        float acc = bm2[t];
        for (int i = 0; i < 128; i++) acc += hb[i] * wm2[i * 2 + t];
        lg[t] = acc;
    }
    __syncthreads();
    if (t == 0) {
        float l0 = lg[0], l1 = lg[1];
        float mx = fmaxf(l0, l1);
        float e0 = expf(l0 - mx), e1 = expf(l1 - mx);
        float s = e0 + e1;
        out[12 + n * 2 + 0] = e0 / s;
        out[12 + n * 2 + 1] = e1 / s;
        ws[WS_WIN + n] = (e1 > e0) ? 1.f : 0.f;
    }
}

// ======================= fallback path: separate kernels (R13-proven) ==========

__global__ __launch_bounds__(256) void prep_kernel(float* ws, const float* wxyz,
        const float* lz, const float* RF3, const float* RFI, const float* w11,
        const float* w12, const float* wpts) {
    prep_body(blockIdx.x, threadIdx.x, ws, wxyz, lz, RF3, RFI, w11, w12, wpts);
}

__global__ __launch_bounds__(256) void mid_kernel(float* ws, const float* wpts,
        const float* w30, const float* b30, const float* w10, const float* b10) {
    __shared__ float px[256], py[256], pz[256], d2[256], rv[256];
    __shared__ int   ri[256];
    __shared__ float wred[4];
    mid_body(blockIdx.x, threadIdx.x, ws, wpts, w30, b30, w10, b10,
             px, py, pz, d2, rv, ri, wred);
}

__global__ __launch_bounds__(256) void mlp23_kernel(float* ws, const float* wpts,
        const float* w20, const float* b20, const float* w21, const float* b21,
        const float* w22, const float* b22,
        const float* w31, const float* b31, const float* w32, const float* b32) {
    __shared__ float sbuf[4896];
    __shared__ float small1[36], small2[36];
    __shared__ int   kn[16];
    mlp23_body(blockIdx.x, threadIdx.x, ws, wpts, w20, b20, w21, b21, w22, b22,
               w31, b31, w32, b32, sbuf, small1, small2, kn);
}

__global__ __launch_bounds__(256) void sim2_kernel(float* ws) {
    __shared__ __align__(16) float dv[64];
    __shared__ float wred[4];
    sim2_body(blockIdx.x, threadIdx.x, ws, dv, wred);
}

__global__ __launch_bounds__(256) void simfeat_kernel(float* ws) {
    __shared__ float wred1[4], wred2[4];
    simfeat_body(blockIdx.x, threadIdx.x, ws, wred1, wred2);
}

__global__ __launch_bounds__(256) void mlp1_kernel(float* ws, const float* w10,
        const float* b11, const float* b12) {
    __shared__ __align__(16) f16 H1h[64 * 136];
    __shared__ __align__(16) f16 H2h[64 * 72];
    __shared__ float base1n[128];
    __shared__ float simw[512];
    __shared__ float rmPart[256];
    int t = threadIdx.x;
    int wave = t >> 6, lane = t & 63, q = lane >> 4, l16 = lane & 15;
    int col = wave * 16 + l16;
    const f16* w11t = (const f16*)(ws + WS_W11T);
    const f16* w12t = (const f16*)(ws + WS_W12T);
    for (int i = t; i < 512; i += 256) simw[i] = w10[134 * 128 + i];
    f16x8 B2f[4], B3f[2];
    for (int s = 0; s < 4; s++) B2f[s] = *(const f16x8*)&w11t[col * 128 + s * 32 + q * 8];
    for (int s = 0; s < 2; s++) B3f[s] = *(const f16x8*)&w12t[col * 64 + s * 32 + q * 8];
    float bias2 = b11[col], bias3 = b12[col];
    mlp1_body(blockIdx.y, blockIdx.x, t, ws, B2f, B3f, bias2, bias3,
              H1h, H2h, base1n, simw, rmPart);
}

__global__ __launch_bounds__(128) void combinehead_kernel(float* ws,
        const float* wm0, const float* bm0, const float* wm1, const float* bm1,
        const float* wm2, const float* bm2, float* out) {
    __shared__ float av[64], ha[64], hb[128], lg[2];
    combinehead_body(blockIdx.x, threadIdx.x, ws, wm0, bm0, wm1, bm1, wm2, bm2, out,
                     av, ha, hb, lg);
}

// ======================= cooperative mega kernel ================================

__global__ __launch_bounds__(256) void mega_kernel(float* ws,
        const float* wxyz, const float* lz, const float* RF3, const float* RFI,
        const float* w11, const float* w12, const float* wpts,
        const float* w30, const float* b30, const float* w10, const float* b10,
        const float* w20, const float* b20, const float* w21, const float* b21,
        const float* w22, const float* b22,
        const float* w31, const float* b31, const float* w32, const float* b32,
        const float* b11, const float* b12,
        const float* wm0, const float* bm0, const float* wm1, const float* bm1,
        const float* wm2, const float* bm2, float* out) {
    cg::grid_group grid = cg::this_grid();
    __shared__ __align__(16) unsigned char smem[30208];
    int t = threadIdx.x;

    for (int b = blockIdx.x; b < 388; b += gridDim.x)
        prep_body(b, t, ws, wxyz, lz, RF3, RFI, w11, w12, wpts);
    grid.sync();

    {
        float* px = (float*)smem;
        float* py = px + 256;
        float* pz = py + 256;
        float* d2 = pz + 256;
        float* rv = d2 + 256;
        int*   ri = (int*)(rv + 256);
        float* wred = (float*)(ri + 256);
        for (int b = blockIdx.x; b < 2177; b += gridDim.x) {
            mid_body(b, t, ws, wpts, w30, b30, w10, b10, px, py, pz, d2, rv, ri, wred);
            __syncthreads();
        }
    }
    grid.sync();

    {
        float* sbuf = (float*)smem;
        float* small1 = sbuf + 4896;
        float* small2 = small1 + 36;
        int* kn = (int*)(small2 + 36);
        for (int b = blockIdx.x; b < 512; b += gridDim.x) {
            mlp23_body(b, t, ws, wpts, w20, b20, w21, b21, w22, b22,
                       w31, b31, w32, b32, sbuf, small1, small2, kn);
            __syncthreads();
        }
    }
    grid.sync();

    {
        float* dv = (float*)smem;
        float* wred = dv + 64;
        for (int b = blockIdx.x; b < 1024; b += gridDim.x) {
            sim2_body(b, t, ws, dv, wred);
            __syncthreads();
        }
    }
    grid.sync();

    {
        float* wred1 = (float*)smem;
        float* wred2 = wred1 + 4;
        for (int b = blockIdx.x; b < 256; b += gridDim.x) {
            simfeat_body(b, t, ws, wred1, wred2);
            __syncthreads();
        }
    }
    grid.sync();

    {
        f16* H1h = (f16*)smem;
        f16* H2h = H1h + 64 * 136;
        float* base1n = (float*)(H2h + 64 * 72);
        float* simw = base1n + 128;
        float* rmPart = simw + 512;
        int wave = t >> 6, lane = t & 63, q = lane >> 4, l16 = lane & 15;
        int col = wave * 16 + l16;
        const f16* w11t = (const f16*)(ws + WS_W11T);
        const f16* w12t = (const f16*)(ws + WS_W12T);
        for (int i = t; i < 512; i += 256) simw[i] = w10[134 * 128 + i];
        f16x8 B2f[4], B3f[2];
        for (int s = 0; s < 4; s++) B2f[s] = *(const f16x8*)&w11t[col * 128 + s * 32 + q * 8];
        for (int s = 0; s < 2; s++) B3f[s] = *(const f16x8*)&w12t[col * 64 + s * 32 + q * 8];
        float bias2 = b11[col], bias3 = b12[col];
        for (int vb = blockIdx.x; vb < 2048; vb += gridDim.x) {
            mlp1_body(vb >> 3, vb & 7, t, ws, B2f, B3f, bias2, bias3,
                      H1h, H2h, base1n, simw, rmPart);
            __syncthreads();
        }
    }
    grid.sync();

    {
        float* av = (float*)smem;
        float* ha = av + 64;
        float* hb = ha + 64;
        float* lg = hb + 128;
        for (int b = blockIdx.x; b < 256; b += gridDim.x) {
            combinehead_body(b, t, ws, wm0, bm0, wm1, bm1, wm2, bm2, out, av, ha, hb, lg);
            __syncthreads();
        }
    }
}

// ---------------- weighted PnP (Kabsch with 3x3 SVD, double) ----------------
__device__ void compute_rt(const double Hm[9], const double sc[3], const double dc[3],
                           float* out) {
    double Hd[3][3] = {{Hm[0], Hm[1], Hm[2]}, {Hm[3], Hm[4], Hm[5]}, {Hm[6], Hm[7], Hm[8]}};
    double A[3][3], V[3][3] = {{1, 0, 0}, {0, 1, 0}, {0, 0, 1}};
    for (int i = 0; i < 3; i++)
        for (int j = 0; j < 3; j++) {
            double s = 0;
            for (int k = 0; k < 3; k++) s += Hd[k][i] * Hd[k][j];
            A[i][j] = s;
        }
    for (int sweep = 0; sweep < 50; sweep++) {
        double off = fabs(A[0][1]) + fabs(A[0][2]) + fabs(A[1][2]);
        if (off < 1e-28) break;
        const int PQ[3][2] = {{0, 1}, {0, 2}, {1, 2}};
        for (int pp = 0; pp < 3; pp++) {
            int p = PQ[pp][0], q = PQ[pp][1];
            double apq = A[p][q];
            if (fabs(apq) < 1e-300) continue;
            double tau = (A[q][q] - A[p][p]) / (2.0 * apq);
            double tt = (tau >= 0.0 ? 1.0 : -1.0) / (fabs(tau) + sqrt(1.0 + tau * tau));
            double c = 1.0 / sqrt(1.0 + tt * tt), s = tt * c;
            for (int k = 0; k < 3; k++) {
                double akp = A[k][p], akq = A[k][q];
                A[k][p] = c * akp - s * akq; A[k][q] = s * akp + c * akq;
            }
            for (int k = 0; k < 3; k++) {
                double apk = A[p][k], aqk = A[q][k];
                A[p][k] = c * apk - s * aqk; A[q][k] = s * apk + c * aqk;
            }
            for (int k = 0; k < 3; k++) {
                double vkp = V[k][p], vkq = V[k][q];
                V[k][p] = c * vkp - s * vkq; V[k][q] = s * vkp + c * vkq;
            }
        }
    }
    double lam[3] = {A[0][0], A[1][1], A[2][2]};
    int o0 = 0, o1 = 1, o2 = 2;
    if (lam[o0] < lam[o1]) { int tp = o0; o0 = o1; o1 = tp; }
    if (lam[o0] < lam[o2]) { int tp = o0; o0 = o2; o2 = tp; }
    if (lam[o1] < lam[o2]) { int tp = o1; o1 = o2; o2 = tp; }
    int ord[3] = {o0, o1, o2};
    double v[3][3], u[3][3], R[3][3];
    for (int k = 0; k < 3; k++)
        for (int i = 0; i < 3; i++) v[k][i] = V[i][ord[k]];
    double sv0 = sqrt(fmax(lam[o0], 0.0));
    if (!(sv0 > 1e-150)) {
        for (int i = 0; i < 3; i++)
            for (int j = 0; j < 3; j++) R[i][j] = (i == j) ? 1.0 : 0.0;
    } else {
        double nn[3];
        for (int k = 0; k < 3; k++) {
            for (int i = 0; i < 3; i++)
                u[k][i] = Hd[i][0] * v[k][0] + Hd[i][1] * v[k][1] + Hd[i][2] * v[k][2];
            nn[k] = sqrt(u[k][0] * u[k][0] + u[k][1] * u[k][1] + u[k][2] * u[k][2]);
        }
        for (int i = 0; i < 3; i++) u[0][i] /= nn[0];
        if (nn[1] > 1e-12 * nn[0]) {
            for (int i = 0; i < 3; i++) u[1][i] /= nn[1];
        } else {
            int e = (fabs(u[0][0]) <= fabs(u[0][1]) && fabs(u[0][0]) <= fabs(u[0][2])) ? 0
                    : ((fabs(u[0][1]) <= fabs(u[0][2])) ? 1 : 2);
            double ev[3] = {0, 0, 0}; ev[e] = 1.0;
            double d0 = ev[0] * u[0][0] + ev[1] * u[0][1] + ev[2] * u[0][2];
            double w1v[3], wn2 = 0;
            for (int i = 0; i < 3; i++) { w1v[i] = ev[i] - d0 * u[0][i]; wn2 += w1v[i] * w1v[i]; }
            wn2 = sqrt(wn2);
            for (int i = 0; i < 3; i++) u[1][i] = w1v[i] / wn2;
        }
        if (nn[2] > 1e-10 * nn[0]) {
            for (int i = 0; i < 3; i++) u[2][i] /= nn[2];
        } else {
            u[2][0] = u[0][1] * u[1][2] - u[0][2] * u[1][1];
            u[2][1] = u[0][2] * u[1][0] - u[0][0] * u[1][2];
            u[2][2] = u[0][0] * u[1][1] - u[0][1] * u[1][0];
        }
        double cr[3] = {u[1][1] * u[2][2] - u[1][2] * u[2][1],
                        u[1][2] * u[2][0] - u[1][0] * u[2][2],
                        u[1][0] * u[2][1] - u[1][1] * u[2][0]};
        double detU = u[0][0] * cr[0] + u[0][1] * cr[1] + u[0][2] * cr[2];
        double cv[3] = {v[1][1] * v[2][2] - v[1][2] * v[2][1],
                        v[1][2] * v[2][0] - v[1][0] * v[2][2],
                        v[1][0] * v[2][1] - v[1][1] * v[2][0]};
        double detV = v[0][0] * cv[0] + v[0][1] * cv[1] + v[0][2] * cv[2];
        double dsign = detU * detV;
        for (int i = 0; i < 3; i++)
            for (int j = 0; j < 3; j++)
                R[i][j] = v[0][i] * u[0][j] + v[1][i] * u[1][j] + dsign * v[2][i] * u[2][j];
    }
    for (int i = 0; i < 3; i++) {
        double ti = dc[i] - (R[i][0] * sc[0] + R[i][1] * sc[1] + R[i][2] * sc[2]);
        out[9 + i] = (float)ti;
        for (int j = 0; j < 3; j++) out[i * 3 + j] = (float)R[i][j];
    }
}

__global__ __launch_bounds__(256) void pnp_kernel(float* ws, float* out) {
    __shared__ double red[9][256];
    int t = threadIdx.x;
    double w = (double)ws[WS_WIN + t];
    double x0 = ws[WS_XYZ + t * 3 + 0];
    double x1 = ws[WS_XYZ + t * 3 + 1];
    double x2 = ws[WS_XYZ + t * 3 + 2];
    double z = x2;
    double dd0 = (double)ws[WS_UV + t * 3 + 0] * z;
    double dd1 = (double)ws[WS_UV + t * 3 + 1] * z;
    double dd2 = z;
    red[0][t] = w;
    red[1][t] = w * x0; red[2][t] = w * x1; red[3][t] = w * x2;
    red[4][t] = w * dd0; red[5][t] = w * dd1; red[6][t] = w * dd2;
    __syncthreads();
    for (int s = 128; s > 0; s >>= 1) {
        if (t < s)
            for (int k = 0; k < 7; k++) red[k][t] += red[k][t + s];
        __syncthreads();
    }
    double wsum = red[0][0];
    double sx0 = red[1][0], sx1 = red[2][0], sx2 = red[3][0];
    double sd0 = red[4][0], sd1 = red[5][0], sd2 = red[6][0];
    __syncthreads();
    double inv = 1.0 / (wsum + 1e-8);
    double sc[3] = {sx0 * inv, sx1 * inv, sx2 * inv};
    double dc[3] = {sd0 * inv, sd1 * inv, sd2 * inv};
    double wn = w * inv;
    double a0 = x0 - sc[0], a1 = x1 - sc[1], a2 = x2 - sc[2];
    double b0 = dd0 - dc[0], b1 = dd1 - dc[1], b2 = dd2 - dc[2];
    red[0][t] = wn * a0 * b0; red[1][t] = wn * a0 * b1; red[2][t] = wn * a0 * b2;
    red[3][t] = wn * a1 * b0; red[4][t] = wn * a1 * b1; red[5][t] = wn * a1 * b2;
    red[6][t] = wn * a2 * b0; red[7][t] = wn * a2 * b1; red[8][t] = wn * a2 * b2;
    __syncthreads();
    for (int s = 128; s > 0; s >>= 1) {
        if (t < s)
            for (int k = 0; k < 9; k++) red[k][t] += red[k][t + s];
        __syncthreads();
    }
    if (t == 0) {
        double Hm[9];
        for (int k = 0; k < 9; k++) Hm[k] = red[k][0];
        compute_rt(Hm, sc, dc, out);
    }
}

// ---------------- launch: coop mega with deterministic fallback ----------------
extern "C" void kernel_launch(void* const* d_in, const int* in_sizes, int n_in,
                              void* d_out, int out_size, void* d_ws, size_t ws_size,
                              hipStream_t stream) {
    float* ws = (float*)d_ws;
    const float* wxyz = (const float*)d_in[0];
    const float* wpts = (const float*)d_in[1];
    const float* RF3  = (const float*)d_in[2];
    const float* RFI  = (const float*)d_in[3];
    const float* lz   = (const float*)d_in[4];
    const float* w2_0 = (const float*)d_in[5];  const float* b2_0 = (const float*)d_in[6];
    const float* w2_1 = (const float*)d_in[7];  const float* b2_1 = (const float*)d_in[8];
    const float* w2_2 = (const float*)d_in[9];  const float* b2_2 = (const float*)d_in[10];
    const float* w3_0 = (const float*)d_in[11]; const float* b3_0 = (const float*)d_in[12];
    const float* w3_1 = (const float*)d_in[13]; const float* b3_1 = (const float*)d_in[14];
    const float* w3_2 = (const float*)d_in[15]; const float* b3_2 = (const float*)d_in[16];
    const float* w1_0 = (const float*)d_in[17]; const float* b1_0 = (const float*)d_in[18];
    const float* w1_1 = (const float*)d_in[19]; const float* b1_1 = (const float*)d_in[20];
    const float* w1_2 = (const float*)d_in[21]; const float* b1_2 = (const float*)d_in[22];
    const float* wm_0 = (const float*)d_in[23]; const float* bm_0 = (const float*)d_in[24];
    const float* wm_1 = (const float*)d_in[25]; const float* bm_1 = (const float*)d_in[26];
    const float* wm_2 = (const float*)d_in[27]; const float* bm_2 = (const float*)d_in[28];
    float* out = (float*)d_out;

    hipError_t rc = hipErrorUnknown;
    int dev = 0;
    if (hipGetDevice(&dev) == hipSuccess) {
        int nCU = 0;
        hipDeviceGetAttribute(&nCU, hipDeviceAttributeMultiprocessorCount, dev);
        if (nCU <= 0) nCU = 256;
        int occ = 0;
        hipOccupancyMaxActiveBlocksPerMultiprocessor(&occ, mega_kernel, 256, 0);
        void* args[] = {
            (void*)&ws, (void*)&wxyz, (void*)&lz, (void*)&RF3, (void*)&RFI,
            (void*)&w1_1, (void*)&w1_2, (void*)&wpts,
            (void*)&w3_0, (void*)&b3_0, (void*)&w1_0, (void*)&b1_0,
            (void*)&w2_0, (void*)&b2_0, (void*)&w2_1, (void*)&b2_1, (void*)&w2_2, (void*)&b2_2,
            (void*)&w3_1, (void*)&b3_1, (void*)&w3_2, (void*)&b3_2,
            (void*)&b1_1, (void*)&b1_2,
            (void*)&wm_0, (void*)&bm_0, (void*)&wm_1, (void*)&bm_1, (void*)&wm_2, (void*)&bm_2,
            (void*)&out
        };
        if (occ >= 1) {
            long cap = (long)occ * (long)nCU;
            int grid = (int)(cap < 2048 ? cap : 2048);
            rc = hipLaunchCooperativeKernel((void*)mega_kernel, dim3(grid), dim3(256),
                                            args, 0, stream);
            if (rc != hipSuccess) {
                (void)hipGetLastError();   // clear sticky error
                // conservative retry: one block per CU (always co-resident)
                rc = hipLaunchCooperativeKernel((void*)mega_kernel, dim3(nCU), dim3(256),
                                                args, 0, stream);
                if (rc != hipSuccess) (void)hipGetLastError();
            }
        }
    }
    if (rc != hipSuccess) {
        // R13-proven 8-dispatch fallback (bitwise-identical values)
        prep_kernel<<<388, 256, 0, stream>>>(ws, wxyz, lz, RF3, RFI, w1_1, w1_2, wpts);
        mid_kernel<<<2177, 256, 0, stream>>>(ws, wpts, w3_0, b3_0, w1_0, b1_0);
        mlp23_kernel<<<512, 256, 0, stream>>>(ws, wpts, w2_0, b2_0, w2_1, b2_1, w2_2, b2_2,
                                              w3_1, b3_1, w3_2, b3_2);
        sim2_kernel<<<1024, 256, 0, stream>>>(ws);
        simfeat_kernel<<<256, 256, 0, stream>>>(ws);
        mlp1_kernel<<<dim3(8, 256), 256, 0, stream>>>(ws, w1_0, b1_1, b1_2);
        combinehead_kernel<<<256, 128, 0, stream>>>(ws, wm_0, bm_0, wm_1, bm_1, wm_2, bm_2, out);
    }
    pnp_kernel<<<1, 256, 0, stream>>>(ws, out);
}

// Round 17
// 221.813 us; speedup vs baseline: 1.0557x; 1.0557x over previous
//
#include <hip/hip_runtime.h>
#include <math.h>

// Problem constants
// B=1, N=256, H=32, W=32, M=1024, C_LIDAR=C_RGB=64, K=16, S=3, MLP3=[128,64,64]

typedef _Float16 f16;
typedef __attribute__((ext_vector_type(4))) _Float16 f16x4;
typedef __attribute__((ext_vector_type(8))) _Float16 f16x8;
typedef __attribute__((ext_vector_type(4))) float f32x4;

// ---------------- workspace layout (float offsets) ----------------
constexpr int WS_XYZ  = 0;                  // 256*3
constexpr int WS_RF   = 768;                // 1024*64
constexpr int WS_RFI  = WS_RF   + 65536;    // 1024*3
constexpr int WS_SN   = WS_RFI  + 3072;     // (reused: RS/RD below)
constexpr int WS_RS   = WS_SN;              // 256 recip norms of wpts rows
constexpr int WS_RD   = WS_SN   + 256;      // 1024 recip norms of RF3 cols
constexpr int WS_WPT  = WS_SN   + 16384;    // 64*256 wpts^T (c-major)
constexpr int WS_SIM1 = WS_WPT  + 65536;    // 1024*256 sim1 TRANSPOSED [n][m]
constexpr int WS_RM1  = WS_SIM1 + 262144;   // 1024 max over n
constexpr int WS_CM1  = WS_RM1  + 1024;     // (unused)
constexpr int WS_PCT  = WS_CM1  + 256;      // 64*256 pcn^T (c-major)
constexpr int WS_IMGF = WS_PCT  + 16384;    // (unused)
constexpr int WS_PCN  = WS_IMGF + 65536;    // (unused, layout keep)
constexpr int WS_IMGN = WS_PCN  + 16384;    // 1024*64 normalized img_feats
constexpr int WS_SIM2 = WS_IMGN + 65536;    // 1024*256 sim2 TRANSPOSED [n][m]
constexpr int WS_RM2  = WS_SIM2 + 262144;   // 1024
constexpr int WS_CM2  = WS_RM2  + 1024;     // (unused)
constexpr int WS_B1   = WS_CM2  + 256;      // 256*128
constexpr int WS_B2   = WS_B1   + 32768;    // 1024*128
constexpr int WS_ATT  = WS_B2   + 131072;   // (unused)
constexpr int WS_UV   = WS_ATT  + 16384;    // 256*3
constexpr int WS_WIN  = WS_UV   + 768;      // 256
constexpr int WS_KNN  = WS_WIN  + 256;      // 256*16 ints
constexpr int WS_PM   = WS_KNN  + 4096;     // 256*8 partial max
constexpr int WS_PS   = WS_PM   + 2048;     // 256*8 partial sum
constexpr int WS_PATT = WS_PS   + 2048;     // 256*8*64 partial att
constexpr int WS_PUV  = WS_PATT + 131072;   // 256*8*3 partial uv
constexpr int WS_W11T = WS_PUV  + 6144;     // 8192 f16 (w1_1^T [col][k])
constexpr int WS_W12T = WS_W11T + 4096;     // 4096 f16 (w1_2^T [col][k])
constexpr int WS_G3   = WS_W12T + 2048;     // 1025*64 (MLP3 layer-1 per-pixel)
constexpr int WS_SIMF = WS_G3   + 65600;    // 256*1024*4 f16 (sim features)
// total ~= 7.06 MB

// ---------------- prep: transposes + f16 weight transposes + recip norms --------
__global__ __launch_bounds__(256) void prep_kernel(float* ws, const float* wxyz,
                                                   const float* lz, const float* RF3,
                                                   const float* RFI, const float* w11,
                                                   const float* w12, const float* wpts) {
    int b = blockIdx.x;
    if (b < 319) {
        int i = b * 256 + threadIdx.x;
        if (i < 768) {
            int n = i / 3;
            ws[WS_XYZ + i] = wxyz[i] * lz[n];
        } else if (i < 768 + 65536) {
            int j = i - 768; int mm = j >> 6, c = j & 63;
            ws[WS_RF + j] = RF3[c * 1024 + mm];
        } else if (i < 768 + 65536 + 3072) {
            int j = i - (768 + 65536); int mm = j / 3, c = j - mm * 3;
            ws[WS_RFI + j] = RFI[c * 1024 + mm];
        } else if (i < 69376 + 8192) {
            int j = i - 69376; int col = j >> 7, k = j & 127;
            ((f16*)(ws + WS_W11T))[col * 128 + k] = (f16)w11[k * 64 + col];
        } else if (i < 69376 + 12288) {
            int j = i - (69376 + 8192); int col = j >> 6, k = j & 63;
            ((f16*)(ws + WS_W12T))[col * 64 + k] = (f16)w12[k * 64 + col];
        }
    } else if (b == 319) {          // wpts row recip norms -> rs[256]
        int n = threadIdx.x;
        float s = 0.f;
        for (int c = 0; c < 64; c++) { float v = wpts[n * 64 + c]; s += v * v; }
        ws[WS_RS + n] = 1.f / fmaxf(sqrtf(s), 1e-12f);
    } else if (b < 324) {           // b in [320,324): RF3 column recip norms -> rd[1024]
        int m = (b - 320) * 256 + threadIdx.x;
        float s = 0.f;
        for (int c = 0; c < 64; c++) { float v = RF3[c * 1024 + m]; s += v * v; }
        ws[WS_RD + m] = 1.f / fmaxf(sqrtf(s), 1e-12f);
    } else {                        // b in [324,388): wpts^T (c-major)
        int i = (b - 324) * 256 + threadIdx.x;
        int c = i >> 8, n = i & 255;
        ws[WS_WPT + c * 256 + n] = wpts[n * 64 + c];
    }
}

// ---------------- mid v4: sim1s (1024) + g3 (257) + base12 (640) + knn (256) ----
// sim1s reads wpts^T coalesced; sim1 stored transposed [n][m].
// knn keeps the LDS-tree (do NOT replace with __shfl_down value+index argmin —
// that variant miscomputed on gfx950, R3-R5).
__global__ __launch_bounds__(256) void mid_kernel(float* ws, const float* wpts,
        const float* w30, const float* b30, const float* w10, const float* b10) {
    int b = blockIdx.x, t = threadIdx.x;
    __shared__ float px[256], py[256], pz[256], d2[256];
    __shared__ float rv[256];
    __shared__ int   ri[256];
    __shared__ float wred[4];
    if (b < 1024) {
        // ---- sim1s: sim1T[n][m] = (rf[m].wpts[n])*rd[m]*rs[n]; rowmax over n ----
        int m = b;
        int wave = t >> 6, lane = t & 63;
        const float* rf = ws + WS_RF;
        const float* wptsT = ws + WS_WPT;
        if (t < 64) px[t] = rf[m * 64 + t];   // dv[64]
        __syncthreads();
        float acc = 0.f;
        for (int c = 0; c < 64; c += 4) {
            acc += px[c]     * wptsT[c * 256 + t]
                 + px[c + 1] * wptsT[(c + 1) * 256 + t]
                 + px[c + 2] * wptsT[(c + 2) * 256 + t]
                 + px[c + 3] * wptsT[(c + 3) * 256 + t];
        }
        acc = acc * ws[WS_RD + m] * ws[WS_RS + t];
        ws[WS_SIM1 + t * 1024 + m] = acc;     // transposed store (scattered, latency-tolerant)
        float mx = acc;
        for (int o = 32; o > 0; o >>= 1) mx = fmaxf(mx, __shfl_down(mx, o));
        if (lane == 0) wred[wave] = mx;
        __syncthreads();
        if (t == 0)
            ws[WS_RM1 + m] = fmaxf(fmaxf(wred[0], wred[1]), fmaxf(wred[2], wred[3]));
    } else if (b < 1281) {
        // ---- g3 (4-way ILP) ----
        int m = (b - 1024) * 4 + (t >> 6), j = t & 63;
        if (m < 1025) {
            float acc;
            if (m < 1024) {
                float a0 = b30[j], a1 = 0.f, a2 = 0.f, a3 = 0.f;
                for (int i = 0; i < 3; i++) a0 += ws[WS_RFI + m * 3 + i] * w30[i * 64 + j];
                const float* rfm = ws + WS_RF + m * 64;
                const float* wp = w30 + 3 * 64 + j;
                for (int c = 0; c < 64; c += 4) {
                    a0 += rfm[c]     * wp[c * 64];
                    a1 += rfm[c + 1] * wp[(c + 1) * 64];
                    a2 += rfm[c + 2] * wp[(c + 2) * 64];
                    a3 += rfm[c + 3] * wp[(c + 3) * 64];
                }
                acc = (a0 + a1) + (a2 + a3);
            } else {
                acc = b30[j];
            }
            ws[WS_G3 + m * 64 + j] = fmaxf(acc, 0.f);
        }
    } else if (b < 1921) {
        // ---- base12 (4-way ILP): 2 rows per block ----
        int bb = (b - 1281) * 2 + (t >> 7);
        int j = t & 127;
        if (bb < 256) {
            int n = bb;
            float a0 = b10[j], a1 = 0.f, a2 = 0.f, a3 = 0.f;
            for (int i = 0; i < 3; i++) a0 += ws[WS_XYZ + n * 3 + i] * w10[i * 128 + j];
            const float* xp = wpts + n * 64;
            const float* wp = w10 + 6 * 128 + j;
            for (int c = 0; c < 64; c += 4) {
                a0 += xp[c]     * wp[c * 128];
                a1 += xp[c + 1] * wp[(c + 1) * 128];
                a2 += xp[c + 2] * wp[(c + 2) * 128];
                a3 += xp[c + 3] * wp[(c + 3) * 128];
            }
            ws[WS_B1 + n * 128 + j] = (a0 + a1) + (a2 + a3);
        } else {
            int m = bb - 256;
            float a0 = 0.f, a1 = 0.f, a2 = 0.f, a3 = 0.f;
            for (int i = 0; i < 3; i++) a0 += ws[WS_RFI + m * 3 + i] * w10[(3 + i) * 128 + j];
            const float* rfm = ws + WS_RF + m * 64;
            const float* wp = w10 + 70 * 128 + j;
            for (int c = 0; c < 64; c += 4) {
                a0 += rfm[c]     * wp[c * 128];
                a1 += rfm[c + 1] * wp[(c + 1) * 128];
                a2 += rfm[c + 2] * wp[(c + 2) * 128];
                a3 += rfm[c + 3] * wp[(c + 3) * 128];
            }
            ws[WS_B2 + m * 128 + j] = (a0 + a1) + (a2 + a3);
        }
    } else {
        // ---- knn ----
        const float* xyz = ws + WS_XYZ;
        int* knn = (int*)(ws + WS_KNN);
        int n = b - 1921;
        px[t] = xyz[t * 3 + 0]; py[t] = xyz[t * 3 + 1]; pz[t] = xyz[t * 3 + 2];
        __syncthreads();
        float dx = px[t] - px[n], dy = py[t] - py[n], dz = pz[t] - pz[n];
        d2[t] = dx * dx + dy * dy + dz * dz;
        __syncthreads();
        for (int k = 0; k < 16; k++) {
            rv[t] = d2[t]; ri[t] = t;
            __syncthreads();
            for (int s = 128; s > 0; s >>= 1) {
                if (t < s) {
                    float v2 = rv[t + s]; int i2 = ri[t + s];
                    if (v2 < rv[t] || (v2 == rv[t] && i2 < ri[t])) { rv[t] = v2; ri[t] = i2; }
                }
                __syncthreads();
            }
            if (t == 0) { knn[n * 16 + k] = ri[0]; d2[ri[0]] = INFINITY; }
            __syncthreads();
        }
    }
}

// ---------------- sim2T[n][m] = imgn[m].pcn[n] via pcn^T; rowmax over n ---------
__global__ __launch_bounds__(256) void sim2_kernel(float* ws) {
    __shared__ __align__(16) float dv[64];
    __shared__ float wred[4];
    int m = blockIdx.x, t = threadIdx.x;
    int wave = t >> 6, lane = t & 63;
    if (t < 64) dv[t] = ws[WS_IMGN + m * 64 + t];
    __syncthreads();
    const float* pcnT = ws + WS_PCT;
    float acc = 0.f;
    for (int c = 0; c < 64; c += 4) {
        acc += dv[c]     * pcnT[c * 256 + t]
             + dv[c + 1] * pcnT[(c + 1) * 256 + t]
             + dv[c + 2] * pcnT[(c + 2) * 256 + t]
             + dv[c + 3] * pcnT[(c + 3) * 256 + t];
    }
    ws[WS_SIM2 + t * 1024 + m] = acc;         // transposed store
    float mx = acc;
    for (int o = 32; o > 0; o >>= 1) mx = fmaxf(mx, __shfl_down(mx, o));
    if (lane == 0) wred[wave] = mx;
    __syncthreads();
    if (t == 0)
        ws[WS_RM2 + m] = fmaxf(fmaxf(wred[0], wred[1]), fmaxf(wred[2], wred[3]));
}

// ---------------- fused colmax(sim1,sim2) + sim-feature precompute (f16x4) ------
// sim reads coalesced (transposed layout); colmax via wave shuffles.
__global__ __launch_bounds__(256) void simfeat_kernel(float* ws) {
    __shared__ float wred1[4], wred2[4];
    int n = blockIdx.x, t = threadIdx.x;
    int wave = t >> 6, lane = t & 63;
    const float* sim1 = ws + WS_SIM1;  const float* rm1g = ws + WS_RM1;
    const float* sim2 = ws + WS_SIM2;  const float* rm2g = ws + WS_RM2;
    f16* simfg = (f16*)(ws + WS_SIMF);
    float s1v[4], s2v[4];
    float mx1 = -INFINITY, mx2 = -INFINITY;
    for (int j = 0; j < 4; j++) {
        int m = t + j * 256;
        s1v[j] = sim1[n * 1024 + m]; mx1 = fmaxf(mx1, s1v[j]);
        s2v[j] = sim2[n * 1024 + m]; mx2 = fmaxf(mx2, s2v[j]);
    }
    float m1 = mx1, m2 = mx2;
    for (int o = 32; o > 0; o >>= 1) {
        m1 = fmaxf(m1, __shfl_down(m1, o));
        m2 = fmaxf(m2, __shfl_down(m2, o));
    }
    if (lane == 0) { wred1[wave] = m1; wred2[wave] = m2; }
    __syncthreads();
    float cm1 = fmaxf(fmaxf(wred1[0], wred1[1]), fmaxf(wred1[2], wred1[3]));
    float cm2 = fmaxf(fmaxf(wred2[0], wred2[1]), fmaxf(wred2[2], wred2[3]));
    for (int j = 0; j < 4; j++) {
        int m = t + j * 256;
        float r1 = rm1g[m], r2 = rm2g[m];
        float f0 = s1v[j] / (cm1 + 1e-6f);
        float f1 = s1v[j] / (r1 + 1e-10f);
        float f2 = s2v[j] / (cm2 + 1e-6f);
        float f3 = s2v[j] / (r2 + 1e-10f);
        *(f16x4*)&simfg[(n * 1024 + m) * 4] =
            (f16x4){(f16)f0, (f16)f1, (f16)f2, (f16)f3};
    }
}

// ---------------- mlp2 (blocks 0..255) + mlp3 (256..511), 4-way ILP GEMVs -------
// mlp2 epilogue writes pcn^T (c-major) for sim2's coalesced reads.
__global__ __launch_bounds__(256) void mlp23_kernel(float* ws, const float* wpts,
        const float* w20, const float* b20, const float* w21, const float* b21,
        const float* w22, const float* b22,
        const float* w31, const float* b31, const float* w32, const float* b32) {
    __shared__ float sbuf[36 * 68 * 2];   // union: mlp2 x/hA/hB (3*1088) | mlp3 x1/h2 (2*2448)
    __shared__ float small1[36], small2[36];
    __shared__ int   kn[16];
    int b = blockIdx.x, t = threadIdx.x;
    if (b < 256) {
        // ---- mlp2 ----
        int n = b;
        float* x  = sbuf;
        float* hA = sbuf + 1088;
        float* hB = sbuf + 2176;
        const float* xyz = ws + WS_XYZ;
        const int* knn = (const int*)(ws + WS_KNN);
        if (t < 16) kn[t] = knn[n * 16 + t];
        __syncthreads();
        for (int i = t; i < 1024; i += 256) {
            int k = i >> 6, c = i & 63;
            x[k * 68 + c] = wpts[kn[k] * 64 + c];
        }
        if (t < 16) {
            int i = kn[t];
            float dx = xyz[i * 3 + 0] - xyz[n * 3 + 0];
            float dy = xyz[i * 3 + 1] - xyz[n * 3 + 1];
            float dz = xyz[i * 3 + 2] - xyz[n * 3 + 2];
            x[t * 68 + 64] = dx; x[t * 68 + 65] = dy; x[t * 68 + 66] = dz;
            x[t * 68 + 67] = sqrtf(dx * dx + dy * dy + dz * dz);
        }
        __syncthreads();
        for (int o = t; o < 1024; o += 256) {
            int k = o >> 6, j = o & 63;
            float a0 = b20[j], a1 = 0.f, a2 = 0.f, a3 = 0.f;
            const float* xr = &x[k * 68];
            const float* wp = w20 + j;
            for (int i = 0; i < 68; i += 4) {
                a0 += xr[i]     * wp[i * 64];
                a1 += xr[i + 1] * wp[(i + 1) * 64];
                a2 += xr[i + 2] * wp[(i + 2) * 64];
                a3 += xr[i + 3] * wp[(i + 3) * 64];
            }
            hA[k * 68 + j] = fmaxf((a0 + a1) + (a2 + a3), 0.f);
        }
        __syncthreads();
        for (int o = t; o < 1024; o += 256) {
            int k = o >> 6, j = o & 63;
            float a0 = b21[j], a1 = 0.f, a2 = 0.f, a3 = 0.f;
            const float* xr = &hA[k * 68];
            const float* wp = w21 + j;
            for (int i = 0; i < 64; i += 4) {
                a0 += xr[i]     * wp[i * 64];
                a1 += xr[i + 1] * wp[(i + 1) * 64];
                a2 += xr[i + 2] * wp[(i + 2) * 64];
                a3 += xr[i + 3] * wp[(i + 3) * 64];
            }
            hB[k * 68 + j] = fmaxf((a0 + a1) + (a2 + a3), 0.f);
        }
        __syncthreads();
        for (int o = t; o < 1024; o += 256) {
            int k = o >> 6, j = o & 63;
            float a0 = b22[j], a1 = 0.f, a2 = 0.f, a3 = 0.f;
            const float* xr = &hB[k * 68];
            const float* wp = w22 + j;
            for (int i = 0; i < 64; i += 4) {
                a0 += xr[i]     * wp[i * 64];
                a1 += xr[i + 1] * wp[(i + 1) * 64];
                a2 += xr[i + 2] * wp[(i + 2) * 64];
                a3 += xr[i + 3] * wp[(i + 3) * 64];
            }
            hA[k * 68 + j] = fmaxf((a0 + a1) + (a2 + a3), 0.f);
        }
        __syncthreads();
        if (t < 16) {
            float mx = -INFINITY;
            for (int j = 0; j < 64; j++) mx = fmaxf(mx, hA[t * 68 + j]);
            small1[t] = mx;
        }
        __syncthreads();
        if (t < 16) {
            float mx = -INFINITY;
            for (int k = 0; k < 16; k++) mx = fmaxf(mx, small1[k]);
            float sum = 0.f;
            for (int k = 0; k < 16; k++) sum += expf(small1[k] - mx);
            small2[t] = expf(small1[t] - mx) / sum;
        }
        __syncthreads();
        if (t < 64) {
            float acc = 0.f;
            for (int k = 0; k < 16; k++) acc += small2[k] * x[k * 68 + t];
            float s = acc * acc;
            for (int o = 32; o > 0; o >>= 1) s += __shfl_down(s, o);
            s = __shfl(s, 0);
            ws[WS_PCT + t * 256 + n] = acc / fmaxf(sqrtf(s), 1e-12f);  // pcn^T
        }
    } else {
        // ---- mlp3 ----
        int m0 = (b - 256) * 4;
        float* x1 = sbuf;
        float* h2 = sbuf + 2448;
        const float* G = ws + WS_G3;
        const float* rf = ws + WS_RF;
        for (int i = t; i < 36 * 64; i += 256) {
            int row = i >> 6, c = i & 63;
            int mi = row / 9, kk = row - mi * 9;
            int m = m0 + mi; int y = m >> 5, x = m & 31;
            int dy = kk / 3 - 1, dx = kk % 3 - 1;
            int ny = y + dy, nx = x + dx;
            bool val = (ny >= 0 && ny < 32 && nx >= 0 && nx < 32);
            int idx = val ? (ny * 32 + nx) : 1024;
            x1[row * 68 + c] = G[idx * 64 + c];
        }
        __syncthreads();
        for (int o = t; o < 36 * 64; o += 256) {
            int row = o >> 6, c = o & 63;
            float a0 = b31[c], a1 = 0.f, a2 = 0.f, a3 = 0.f;
            const float* xr = &x1[row * 68];
            const float* wp = w31 + c;
            for (int i = 0; i < 64; i += 4) {
                a0 += xr[i]     * wp[i * 64];
                a1 += xr[i + 1] * wp[(i + 1) * 64];
                a2 += xr[i + 2] * wp[(i + 2) * 64];
                a3 += xr[i + 3] * wp[(i + 3) * 64];
            }
            h2[row * 68 + c] = fmaxf((a0 + a1) + (a2 + a3), 0.f);
        }
        __syncthreads();
        for (int o = t; o < 36 * 64; o += 256) {
            int row = o >> 6, c = o & 63;
            float a0 = b32[c], a1 = 0.f, a2 = 0.f, a3 = 0.f;
            const float* xr = &h2[row * 68];
            const float* wp = w32 + c;
            for (int i = 0; i < 64; i += 4) {
                a0 += xr[i]     * wp[i * 64];
                a1 += xr[i + 1] * wp[(i + 1) * 64];
                a2 += xr[i + 2] * wp[(i + 2) * 64];
                a3 += xr[i + 3] * wp[(i + 3) * 64];
            }
            x1[row * 68 + c] = fmaxf((a0 + a1) + (a2 + a3), 0.f);
        }
        __syncthreads();
        if (t < 36) {
            float mx = -INFINITY;
            for (int c = 0; c < 64; c++) mx = fmaxf(mx, x1[t * 68 + c]);
            small1[t] = mx;
        }
        __syncthreads();
        if (t < 36) {
            int mi = t / 9;
            float mx = -INFINITY;
            for (int k = 0; k < 9; k++) mx = fmaxf(mx, small1[mi * 9 + k]);
            float sum = 0.f;
            for (int k = 0; k < 9; k++) sum += expf(small1[mi * 9 + k] - mx);
            small2[t] = expf(small1[t] - mx) / sum;
        }
        __syncthreads();
        {
            int mi = t >> 6, c = t & 63;   // wave mi handles m0+mi, lane c
            int m = m0 + mi; int y = m >> 5, x = m & 31;
            float acc = 0.f;
            for (int kk = 0; kk < 9; kk++) {
                int dy = kk / 3 - 1, dx = kk % 3 - 1;
                int ny = y + dy, nx = x + dx;
                bool val = (ny >= 0 && ny < 32 && nx >= 0 && nx < 32);
                if (val) acc += small2[mi * 9 + kk] * rf[(ny * 32 + nx) * 64 + c];
            }
            float s = acc * acc;
            for (int o = 32; o > 0; o >>= 1) s += __shfl_down(s, o);
            s = __shfl(s, 0);
            ws[WS_IMGN + m * 64 + c] = acc / fmaxf(sqrtf(s), 1e-12f);
        }
    }
}

// ---------------- main fused MLP1 v4 (R8/R9-proven; VGPR 64, do NOT hoist
// layer-1 LDS vectors into registers — R10 showed it costs occupancy) ----------
__global__ __launch_bounds__(256) void mlp1_kernel(float* ws, const float* w10,
        const float* b11, const float* b12) {
    __shared__ __align__(16) f16 H1h[64 * 136];
    __shared__ __align__(16) f16 H2h[64 * 72];
    __shared__ float base1n[128];
    __shared__ float simw[4 * 128];
    __shared__ float rmPart[4][64];
    int n = blockIdx.y, seg = blockIdx.x, t = threadIdx.x;
    int wave = t >> 6, lane = t & 63, q = lane >> 4, l16 = lane & 15;
    int col = wave * 16 + l16;
    const float* base2 = ws + WS_B2;
    const float* rfig = ws + WS_RFI;
    const f16* simfg = (const f16*)(ws + WS_SIMF);
    const f16* w11t = (const f16*)(ws + WS_W11T);
    const f16* w12t = (const f16*)(ws + WS_W12T);
    if (t < 128) base1n[t] = ws[WS_B1 + n * 128 + t];
    for (int i = t; i < 512; i += 256) simw[i] = w10[134 * 128 + i];
    f16x8 B2f[4], B3f[2];
    for (int s = 0; s < 4; s++) B2f[s] = *(const f16x8*)&w11t[col * 128 + s * 32 + q * 8];
    for (int s = 0; s < 2; s++) B3f[s] = *(const f16x8*)&w12t[col * 64 + s * 32 + q * 8];
    float bias2 = b11[col], bias3 = b12[col];
    float attAcc = 0.f;
    float uv0 = 0.f, uv1 = 0.f, uv2 = 0.f;
    float Mv = -INFINITY, Sv = 0.f;
    int mBeg = seg * 128;
    __syncthreads();
    for (int c4 = 0; c4 < 2; c4++) {
        int m0 = mBeg + c4 * 64;
        for (int idx = t; idx < 2048; idx += 256) {
            int row = idx >> 5, k4 = (idx & 31) * 4;
            int m = m0 + row;
            f16x4 sf = *(const f16x4*)&simfg[(n * 1024 + m) * 4];
            float s0 = (float)sf[0], s1 = (float)sf[1], s2 = (float)sf[2], s3 = (float)sf[3];
            float4 bs = *(const float4*)&base2[m * 128 + k4];
            float4 b1v = *(const float4*)&base1n[k4];
            float4 w0v = *(const float4*)&simw[k4];
            float4 w1v = *(const float4*)&simw[128 + k4];
            float4 w2v = *(const float4*)&simw[256 + k4];
            float4 w3v = *(const float4*)&simw[384 + k4];
            float v0 = b1v.x + bs.x + s0 * w0v.x + s1 * w1v.x + s2 * w2v.x + s3 * w3v.x;
            float v1 = b1v.y + bs.y + s0 * w0v.y + s1 * w1v.y + s2 * w2v.y + s3 * w3v.y;
            float v2 = b1v.z + bs.z + s0 * w0v.z + s1 * w1v.z + s2 * w2v.z + s3 * w3v.z;
            float v3 = b1v.w + bs.w + s0 * w0v.w + s1 * w1v.w + s2 * w2v.w + s3 * w3v.w;
            *(f16x4*)&H1h[row * 136 + k4] = (f16x4){
                (f16)fmaxf(v0, 0.f), (f16)fmaxf(v1, 0.f),
                (f16)fmaxf(v2, 0.f), (f16)fmaxf(v3, 0.f)};
        }
        __syncthreads();
        f32x4 a[4];
        for (int tl = 0; tl < 4; tl++) a[tl] = (f32x4){bias2, bias2, bias2, bias2};
        for (int s = 0; s < 4; s++)
            for (int tl = 0; tl < 4; tl++) {
                f16x8 f = *(const f16x8*)&H1h[(tl * 16 + l16) * 136 + s * 32 + q * 8];
                a[tl] = __builtin_amdgcn_mfma_f32_16x16x32_f16(f, B2f[s], a[tl], 0, 0, 0);
            }
        for (int tl = 0; tl < 4; tl++)
            for (int r = 0; r < 4; r++)
                H2h[(tl * 16 + q * 4 + r) * 72 + col] = (f16)fmaxf(a[tl][r], 0.f);
        __syncthreads();
        f32x4 c3[4];
        for (int tl = 0; tl < 4; tl++) c3[tl] = (f32x4){bias3, bias3, bias3, bias3};
        for (int s = 0; s < 2; s++)
            for (int tl = 0; tl < 4; tl++) {
                f16x8 f = *(const f16x8*)&H2h[(tl * 16 + l16) * 72 + s * 32 + q * 8];
                c3[tl] = __builtin_amdgcn_mfma_f32_16x16x32_f16(f, B3f[s], c3[tl], 0, 0, 0);
            }
        for (int tl = 0; tl < 4; tl++)
            for (int r = 0; r < 4; r++)
                c3[tl][r] = fmaxf(c3[tl][r], 0.f);
        for (int tl = 0; tl < 4; tl++)
            for (int r = 0; r < 4; r++) {
                float v = c3[tl][r];
                v = fmaxf(v, __shfl_xor(v, 1));
                v = fmaxf(v, __shfl_xor(v, 2));
                v = fmaxf(v, __shfl_xor(v, 4));
                v = fmaxf(v, __shfl_xor(v, 8));
                if (l16 == 0) rmPart[wave][tl * 16 + q * 4 + r] = v;
            }
        __syncthreads();
        float rmv = fmaxf(fmaxf(rmPart[0][lane], rmPart[1][lane]),
                          fmaxf(rmPart[2][lane], rmPart[3][lane]));
        float tv = rmv;
        for (int off = 32; off > 0; off >>= 1) tv = fmaxf(tv, __shfl_xor(tv, off));
        float newM = fmaxf(Mv, tv);
        float rescale = __expf(Mv - newM);
        float ewv = __expf(rmv - newM);
        Mv = newM;
        float se = ewv;
        for (int off = 32; off > 0; off >>= 1) se += __shfl_xor(se, off);
        Sv = Sv * rescale + se;
        float ap = 0.f;
        for (int tl = 0; tl < 4; tl++)
            for (int r = 0; r < 4; r++)
                ap += __shfl(ewv, tl * 16 + q * 4 + r) * c3[tl][r];
        ap += __shfl_xor(ap, 16);
        ap += __shfl_xor(ap, 32);
        if (lane < 16) attAcc = attAcc * rescale + ap;
        if (wave == 0) {
            const float* rp = &rfig[(m0 + lane) * 3];
            float u0 = ewv * rp[0], u1 = ewv * rp[1], u2 = ewv * rp[2];
            for (int off = 32; off > 0; off >>= 1) {
                u0 += __shfl_xor(u0, off);
                u1 += __shfl_xor(u1, off);
                u2 += __shfl_xor(u2, off);
            }
            uv0 = uv0 * rescale + u0;
            uv1 = uv1 * rescale + u1;
            uv2 = uv2 * rescale + u2;
        }
    }
    int p = n * 8 + seg;
    if (t == 0) {
        ws[WS_PM + p] = Mv; ws[WS_PS + p] = Sv;
        ws[WS_PUV + p * 3 + 0] = uv0;
        ws[WS_PUV + p * 3 + 1] = uv1;
        ws[WS_PUV + p * 3 + 2] = uv2;
    }
    if (lane < 16) ws[WS_PATT + p * 64 + wave * 16 + lane] = attAcc;
}

// ---------------- fused combine (8 segs) + head MLP -> weights, w_in, uv ---------
__global__ __launch_bounds__(128) void combinehead_kernel(float* ws,
        const float* wm0, const float* bm0, const float* wm1, const float* bm1,
        const float* wm2, const float* bm2, float* out) {
    __shared__ float av[64], ha[64], hb[128], lg[2];
    int n = blockIdx.x, t = threadIdx.x;
    float pm[8], e[8];
    float M = -INFINITY;
    for (int s = 0; s < 8; s++) { pm[s] = ws[WS_PM + n * 8 + s]; M = fmaxf(M, pm[s]); }
    float S = 0.f;
    for (int s = 0; s < 8; s++) { e[s] = expf(pm[s] - M); S += ws[WS_PS + n * 8 + s] * e[s]; }
    if (t < 64) {
        float acc = 0.f;
        for (int s = 0; s < 8; s++) acc += ws[WS_PATT + (n * 8 + s) * 64 + t] * e[s];
        av[t] = acc / S;
    } else if (t < 67) {
        int c = t - 64; float acc = 0.f;
        for (int s = 0; s < 8; s++) acc += ws[WS_PUV + (n * 8 + s) * 3 + c] * e[s];
        ws[WS_UV + n * 3 + c] = acc / S;
    }
    __syncthreads();
    if (t < 64) {
        float acc = bm0[t];
        for (int i = 0; i < 64; i++) acc += av[i] * wm0[i * 64 + t];
        ha[t] = fmaxf(acc, 0.f);
    }
    __syncthreads();
    {
        float acc = bm1[t];
        for (int i = 0; i < 64; i++) acc += ha[i] * wm1[i * 128 + t];
        hb[t] = fmaxf(acc, 0.f);
    }
    __syncthreads();
    if (t < 2) {
        float acc = bm2[t];
        for (int i = 0; i < 128; i++) acc += hb[i] * wm2[i * 2 + t];
        lg[t] = acc;
    }
    __syncthreads();
    if (t == 0) {
        float l0 = lg[0], l1 = lg[1];
        float mx = fmaxf(l0, l1);
        float e0 = expf(l0 - mx), e1 = expf(l1 - mx);
        float s = e0 + e1;
        out[12 + n * 2 + 0] = e0 / s;
        out[12 + n * 2 + 1] = e1 / s;
        ws[WS_WIN + n] = (e1 > e0) ? 1.f : 0.f;
    }
}

// ---------------- weighted PnP (Kabsch with 3x3 SVD, double) ----------------
__device__ void compute_rt(const double Hm[9], const double sc[3], const double dc[3],
                           float* out) {
    double Hd[3][3] = {{Hm[0], Hm[1], Hm[2]}, {Hm[3], Hm[4], Hm[5]}, {Hm[6], Hm[7], Hm[8]}};
    double A[3][3], V[3][3] = {{1, 0, 0}, {0, 1, 0}, {0, 0, 1}};
    for (int i = 0; i < 3; i++)
        for (int j = 0; j < 3; j++) {
            double s = 0;
            for (int k = 0; k < 3; k++) s += Hd[k][i] * Hd[k][j];
            A[i][j] = s;
        }
    for (int sweep = 0; sweep < 50; sweep++) {
        double off = fabs(A[0][1]) + fabs(A[0][2]) + fabs(A[1][2]);
        if (off < 1e-28) break;
        const int PQ[3][2] = {{0, 1}, {0, 2}, {1, 2}};
        for (int pp = 0; pp < 3; pp++) {
            int p = PQ[pp][0], q = PQ[pp][1];
            double apq = A[p][q];
            if (fabs(apq) < 1e-300) continue;
            double tau = (A[q][q] - A[p][p]) / (2.0 * apq);
            double tt = (tau >= 0.0 ? 1.0 : -1.0) / (fabs(tau) + sqrt(1.0 + tau * tau));
            double c = 1.0 / sqrt(1.0 + tt * tt), s = tt * c;
            for (int k = 0; k < 3; k++) {
                double akp = A[k][p], akq = A[k][q];
                A[k][p] = c * akp - s * akq; A[k][q] = s * akp + c * akq;
            }
            for (int k = 0; k < 3; k++) {
                double apk = A[p][k], aqk = A[q][k];
                A[p][k] = c * apk - s * aqk; A[q][k] = s * apk + c * aqk;
            }
            for (int k = 0; k < 3; k++) {
                double vkp = V[k][p], vkq = V[k][q];
                V[k][p] = c * vkp - s * vkq; V[k][q] = s * vkp + c * vkq;
            }
        }
    }
    double lam[3] = {A[0][0], A[1][1], A[2][2]};
    int o0 = 0, o1 = 1, o2 = 2;
    if (lam[o0] < lam[o1]) { int tp = o0; o0 = o1; o1 = tp; }
    if (lam[o0] < lam[o2]) { int tp = o0; o0 = o2; o2 = tp; }
    if (lam[o1] < lam[o2]) { int tp = o1; o1 = o2; o2 = tp; }
    int ord[3] = {o0, o1, o2};
    double v[3][3], u[3][3], R[3][3];
    for (int k = 0; k < 3; k++)
        for (int i = 0; i < 3; i++) v[k][i] = V[i][ord[k]];
    double sv0 = sqrt(fmax(lam[o0], 0.0));
    if (!(sv0 > 1e-150)) {
        for (int i = 0; i < 3; i++)
            for (int j = 0; j < 3; j++) R[i][j] = (i == j) ? 1.0 : 0.0;
    } else {
        double nn[3];
        for (int k = 0; k < 3; k++) {
            for (int i = 0; i < 3; i++)
                u[k][i] = Hd[i][0] * v[k][0] + Hd[i][1] * v[k][1] + Hd[i][2] * v[k][2];
            nn[k] = sqrt(u[k][0] * u[k][0] + u[k][1] * u[k][1] + u[k][2] * u[k][2]);
        }
        for (int i = 0; i < 3; i++) u[0][i] /= nn[0];
        if (nn[1] > 1e-12 * nn[0]) {
            for (int i = 0; i < 3; i++) u[1][i] /= nn[1];
        } else {
            int e = (fabs(u[0][0]) <= fabs(u[0][1]) && fabs(u[0][0]) <= fabs(u[0][2])) ? 0
                    : ((fabs(u[0][1]) <= fabs(u[0][2])) ? 1 : 2);
            double ev[3] = {0, 0, 0}; ev[e] = 1.0;
            double d0 = ev[0] * u[0][0] + ev[1] * u[0][1] + ev[2] * u[0][2];
            double w1v[3], wn2 = 0;
            for (int i = 0; i < 3; i++) { w1v[i] = ev[i] - d0 * u[0][i]; wn2 += w1v[i] * w1v[i]; }
            wn2 = sqrt(wn2);
            for (int i = 0; i < 3; i++) u[1][i] = w1v[i] / wn2;
        }
        if (nn[2] > 1e-10 * nn[0]) {
            for (int i = 0; i < 3; i++) u[2][i] /= nn[2];
        } else {
            u[2][0] = u[0][1] * u[1][2] - u[0][2] * u[1][1];
            u[2][1] = u[0][2] * u[1][0] - u[0][0] * u[1][2];
            u[2][2] = u[0][0] * u[1][1] - u[0][1] * u[1][0];
        }
        double cr[3] = {u[1][1] * u[2][2] - u[1][2] * u[2][1],
                        u[1][2] * u[2][0] - u[1][0] * u[2][2],
                        u[1][0] * u[2][1] - u[1][1] * u[2][0]};
        double detU = u[0][0] * cr[0] + u[0][1] * cr[1] + u[0][2] * cr[2];
        double cv[3] = {v[1][1] * v[2][2] - v[1][2] * v[2][1],
                        v[1][2] * v[2][0] - v[1][0] * v[2][2],
                        v[1][0] * v[2][1] - v[1][1] * v[2][0]};
        double detV = v[0][0] * cv[0] + v[0][1] * cv[1] + v[0][2] * cv[2];
        double dsign = detU * detV;
        for (int i = 0; i < 3; i++)
            for (int j = 0; j < 3; j++)
                R[i][j] = v[0][i] * u[0][j] + v[1][i] * u[1][j] + dsign * v[2][i] * u[2][j];
    }
    for (int i = 0; i < 3; i++) {
        double ti = dc[i] - (R[i][0] * sc[0] + R[i][1] * sc[1] + R[i][2] * sc[2]);
        out[9 + i] = (float)ti;
        for (int j = 0; j < 3; j++) out[i * 3 + j] = (float)R[i][j];
    }
}

__global__ __launch_bounds__(256) void pnp_kernel(float* ws, float* out) {
    __shared__ double red[9][256];
    int t = threadIdx.x;
    double w = (double)ws[WS_WIN + t];
    double x0 = ws[WS_XYZ + t * 3 + 0];
    double x1 = ws[WS_XYZ + t * 3 + 1];
    double x2 = ws[WS_XYZ + t * 3 + 2];
    double z = x2;
    double dd0 = (double)ws[WS_UV + t * 3 + 0] * z;
    double dd1 = (double)ws[WS_UV + t * 3 + 1] * z;
    double dd2 = z;
    red[0][t] = w;
    red[1][t] = w * x0; red[2][t] = w * x1; red[3][t] = w * x2;
    red[4][t] = w * dd0; red[5][t] = w * dd1; red[6][t] = w * dd2;
    __syncthreads();
    for (int s = 128; s > 0; s >>= 1) {
        if (t < s)
            for (int k = 0; k < 7; k++) red[k][t] += red[k][t + s];
        __syncthreads();
    }
    double wsum = red[0][0];
    double sx0 = red[1][0], sx1 = red[2][0], sx2 = red[3][0];
    double sd0 = red[4][0], sd1 = red[5][0], sd2 = red[6][0];
    __syncthreads();
    double inv = 1.0 / (wsum + 1e-8);
    double sc[3] = {sx0 * inv, sx1 * inv, sx2 * inv};
    double dc[3] = {sd0 * inv, sd1 * inv, sd2 * inv};
    double wn = w * inv;
    double a0 = x0 - sc[0], a1 = x1 - sc[1], a2 = x2 - sc[2];
    double b0 = dd0 - dc[0], b1 = dd1 - dc[1], b2 = dd2 - dc[2];
    red[0][t] = wn * a0 * b0; red[1][t] = wn * a0 * b1; red[2][t] = wn * a0 * b2;
    red[3][t] = wn * a1 * b0; red[4][t] = wn * a1 * b1; red[5][t] = wn * a1 * b2;
    red[6][t] = wn * a2 * b0; red[7][t] = wn * a2 * b1; red[8][t] = wn * a2 * b2;
    __syncthreads();
    for (int s = 128; s > 0; s >>= 1) {
        if (t < s)
            for (int k = 0; k < 9; k++) red[k][t] += red[k][t + s];
        __syncthreads();
    }
    if (t == 0) {
        double Hm[9];
        for (int k = 0; k < 9; k++) Hm[k] = red[k][0];
        compute_rt(Hm, sc, dc, out);
    }
}

// ---------------- launch (8 dispatches) ----------------
extern "C" void kernel_launch(void* const* d_in, const int* in_sizes, int n_in,
                              void* d_out, int out_size, void* d_ws, size_t ws_size,
                              hipStream_t stream) {
    float* ws = (float*)d_ws;
    const float* wxyz = (const float*)d_in[0];
    const float* wpts = (const float*)d_in[1];
    const float* RF3  = (const float*)d_in[2];
    const float* RFI  = (const float*)d_in[3];
    const float* lz   = (const float*)d_in[4];
    const float* w2_0 = (const float*)d_in[5];  const float* b2_0 = (const float*)d_in[6];
    const float* w2_1 = (const float*)d_in[7];  const float* b2_1 = (const float*)d_in[8];
    const float* w2_2 = (const float*)d_in[9];  const float* b2_2 = (const float*)d_in[10];
    const float* w3_0 = (const float*)d_in[11]; const float* b3_0 = (const float*)d_in[12];
    const float* w3_1 = (const float*)d_in[13]; const float* b3_1 = (const float*)d_in[14];
    const float* w3_2 = (const float*)d_in[15]; const float* b3_2 = (const float*)d_in[16];
    const float* w1_0 = (const float*)d_in[17]; const float* b1_0 = (const float*)d_in[18];
    const float* w1_1 = (const float*)d_in[19]; const float* b1_1 = (const float*)d_in[20];
    const float* w1_2 = (const float*)d_in[21]; const float* b1_2 = (const float*)d_in[22];
    const float* wm_0 = (const float*)d_in[23]; const float* bm_0 = (const float*)d_in[24];
    const float* wm_1 = (const float*)d_in[25]; const float* bm_1 = (const float*)d_in[26];
    const float* wm_2 = (const float*)d_in[27]; const float* bm_2 = (const float*)d_in[28];
    float* out = (float*)d_out;

    prep_kernel<<<388, 256, 0, stream>>>(ws, wxyz, lz, RF3, RFI, w1_1, w1_2, wpts);
    mid_kernel<<<2177, 256, 0, stream>>>(ws, wpts, w3_0, b3_0, w1_0, b1_0);
    mlp23_kernel<<<512, 256, 0, stream>>>(ws, wpts, w2_0, b2_0, w2_1, b2_1, w2_2, b2_2,
                                          w3_1, b3_1, w3_2, b3_2);
    sim2_kernel<<<1024, 256, 0, stream>>>(ws);
    simfeat_kernel<<<256, 256, 0, stream>>>(ws);
    mlp1_kernel<<<dim3(8, 256), 256, 0, stream>>>(ws, w1_0, b1_1, b1_2);
    combinehead_kernel<<<256, 128, 0, stream>>>(ws, wm_0, bm_0, wm_1, bm_1, wm_2, bm_2, out);
    pnp_kernel<<<1, 256, 0, stream>>>(ws, out);
}